// Round 4
// baseline (277.783 us; speedup 1.0000x reference)
//
#include <hip/hip_runtime.h>
#include <hip/hip_fp16.h>
#include <stdint.h>

typedef __attribute__((ext_vector_type(4))) int int32x4;

#define TOKENS 8192
#define IN_F   4096
#define OUT_F  4096
#define BM 128
#define BN 128
#define BK 64   // int8 elements per K-step (64 bytes per row)

// ---- pack int32 (harness container for int8) -> int8 ----
__global__ __launch_bounds__(256)
void pack_kernel(const int* __restrict__ src, int8_t* __restrict__ dst, int n)
{
    const int base = (blockIdx.x * 256 + threadIdx.x) * 16;
    if (base >= n) return;
    int8_t tmp[16];
#pragma unroll
    for (int j = 0; j < 16; j += 4) {
        int32x4 v = *(const int32x4*)(src + base + j);
        tmp[j + 0] = (int8_t)v[0];
        tmp[j + 1] = (int8_t)v[1];
        tmp[j + 2] = (int8_t)v[2];
        tmp[j + 3] = (int8_t)v[3];
    }
    *(int32x4*)(dst + base) = *(const int32x4*)tmp;
}

// 256 threads = 4 waves in a 2x2 grid; each wave owns a 64x64 output sub-tile
// computed as 4x4 fragments of mfma_i32_16x16x64_i8.
__global__ __launch_bounds__(256, 2)
void w8a8_gemm_kernel(const int8_t* __restrict__ x,
                      const int8_t* __restrict__ w,
                      const float* __restrict__ scale,
                      const float* __restrict__ bias,
                      float* __restrict__ out)
{
    __shared__ int8_t lA[BM * BK];   // [128][64] linear, 8 KB
    __shared__ int8_t lB[BN * BK];   // [128][64] linear, 8 KB

    const int tid   = threadIdx.x;
    const int wave  = tid >> 6;
    const int lane  = tid & 63;
    const int waveM = wave >> 1;     // 0..1
    const int waveN = wave & 1;      // 0..1

    const int bn = blockIdx.x;       // 0..31  (N tiles)
    const int bm = blockIdx.y;       // 0..63  (M tiles)

    const int8_t* gA = x + (size_t)bm * BM * IN_F;
    const int8_t* gB = w + (size_t)bn * BN * IN_F;

    // staging: each global_load_lds issue = 64 lanes x 16 B = 1024 B = 16 rows.
    const int srow = lane >> 2;          // 0..15 within segment
    const int scol = (lane & 3) << 4;    // 0,16,32,48

    // fragment read: row/col = lane&15, k-bytes = (lane>>4)*16 .. +15
    const int fr = lane & 15;
    const int kc = (lane >> 4) << 4;

    int32x4 acc[4][4];
#pragma unroll
    for (int m = 0; m < 4; ++m)
#pragma unroll
        for (int n = 0; n < 4; ++n)
            acc[m][n] = (int32x4){0, 0, 0, 0};

    for (int kt = 0; kt < IN_F; kt += BK) {
        // ---- stage A and B tiles (async global -> LDS, 16 B/lane) ----
#pragma unroll
        for (int i = 0; i < 2; ++i) {
            const int seg = wave * 2 + i;   // 0..7, 16 rows each
            __builtin_amdgcn_global_load_lds(
                (__attribute__((address_space(1))) void*)(gA + (size_t)(seg * 16 + srow) * IN_F + kt + scol),
                (__attribute__((address_space(3))) void*)(&lA[seg * 1024]),
                16, 0, 0);
            __builtin_amdgcn_global_load_lds(
                (__attribute__((address_space(1))) void*)(gB + (size_t)(seg * 16 + srow) * IN_F + kt + scol),
                (__attribute__((address_space(3))) void*)(&lB[seg * 1024]),
                16, 0, 0);
        }
        __syncthreads();   // drains vmcnt before any wave reads LDS

        // ---- LDS -> fragments ----
        int32x4 a[4], b[4];
#pragma unroll
        for (int m = 0; m < 4; ++m)
            a[m] = *(const int32x4*)&lA[(waveM * 64 + m * 16 + fr) * BK + kc];
#pragma unroll
        for (int n = 0; n < 4; ++n)
            b[n] = *(const int32x4*)&lB[(waveN * 64 + n * 16 + fr) * BK + kc];

        // ---- MFMA: 16 x (16x16x64 i8) per wave per K-step ----
#pragma unroll
        for (int m = 0; m < 4; ++m)
#pragma unroll
            for (int n = 0; n < 4; ++n)
                acc[m][n] = __builtin_amdgcn_mfma_i32_16x16x64_i8(a[m], b[n], acc[m][n], 0, 0, 0);

        __syncthreads();   // all reads done before next stage overwrites
    }

    // ---- epilogue: dequant + bias with fp16 rounding (match ref), store f32 ----
    // C/D layout: col = lane&15, row = (lane>>4)*4 + reg  (dtype-independent, verified)
    const int r0 = (lane >> 4) << 2;
#pragma unroll
    for (int nf = 0; nf < 4; ++nf) {
        const int col = bn * BN + waveN * 64 + nf * 16 + fr;
        const float sc = scale[col];                 // f32 container of fp16 value
        const __half bs = __float2half(bias[col]);   // exact (value is an fp16)
#pragma unroll
        for (int mf = 0; mf < 4; ++mf) {
            const int rowb = bm * BM + waveM * 64 + mf * 16 + r0;
#pragma unroll
            for (int r = 0; r < 4; ++r) {
                // reference: f16(acc_f32 * scale_f32) then f16 add bias; store f32
                __half h = __float2half((float)acc[mf][nf][r] * sc);
                out[(size_t)(rowb + r) * OUT_F + col] = __half2float(__hadd(h, bs));
            }
        }
    }
}

// second tuple output: copy of bias (f32 container)
__global__ void bias_copy_kernel(const float* __restrict__ bias, float* __restrict__ dst)
{
    const int i = blockIdx.x * 256 + threadIdx.x;
    if (i < OUT_F) dst[i] = bias[i];
}

extern "C" void kernel_launch(void* const* d_in, const int* in_sizes, int n_in,
                              void* d_out, int out_size, void* d_ws, size_t ws_size,
                              hipStream_t stream)
{
    const int*   x32   = (const int*)d_in[0];     // int8 values in int32 container
    const int*   w32   = (const int*)d_in[1];
    const float* scale = (const float*)d_in[2];   // fp16 values in f32 container
    const float* bias  = (const float*)d_in[3];
    float* out = (float*)d_out;

    // pack into workspace: x8 = 32 MB, w8 = 16 MB
    int8_t* x8 = (int8_t*)d_ws;
    int8_t* w8 = x8 + (size_t)TOKENS * IN_F;

    const int nx = TOKENS * IN_F;   // 33,554,432
    const int nw = OUT_F * IN_F;    // 16,777,216
    pack_kernel<<<nx / (256 * 16), 256, 0, stream>>>(x32, x8, nx);
    pack_kernel<<<nw / (256 * 16), 256, 0, stream>>>(w32, w8, nw);

    dim3 grid(OUT_F / BN, TOKENS / BM);   // (32, 64) = 2048 blocks
    w8a8_gemm_kernel<<<grid, 256, 0, stream>>>(x8, w8, scale, bias, out);
    bias_copy_kernel<<<OUT_F / 256, 256, 0, stream>>>(bias, out + (size_t)TOKENS * OUT_F);
}

// Round 6
// 231.992 us; speedup vs baseline: 1.1974x; 1.1974x over previous
//
#include <hip/hip_runtime.h>
#include <hip/hip_fp16.h>
#include <stdint.h>

typedef __attribute__((ext_vector_type(4))) int int32x4;

#define TOKENS 8192
#define IN_F   4096
#define OUT_F  4096
#define BM 256
#define BN 256
#define BK 128              // int8 per K-tile = 128 B rows
#define NT (IN_F / BK)      // 32 K-tiles

// ---------------- pack int32 container -> int8 (coalesced) ----------------
__global__ __launch_bounds__(256)
void pack_kernel(const int* __restrict__ src, uint32_t* __restrict__ dst, int n4)
{
    for (int i = blockIdx.x * 256 + threadIdx.x; i < n4; i += gridDim.x * 256) {
        int32x4 v = ((const int32x4*)src)[i];           // 16 B/lane coalesced
        dst[i] = (uint32_t)(v[0] & 0xff) | ((uint32_t)(v[1] & 0xff) << 8) |
                 ((uint32_t)(v[2] & 0xff) << 16) | ((uint32_t)v[3] << 24);
    }
}

// ---------------- 256x256 8-phase i8 GEMM (T2+T3+T5, lead-1-tile) ----------
// 512 threads = 8 waves (2M x 4N). Per-wave output 128x64 = 8m x 4n fragments
// of mfma_i32_16x16x64_i8, BK=128 = 2 k-steps. 4 gray-code phases per K-tile
// (16 MFMA each). All 4 half-tiles of tile t+1 staged at top of tile t into
// the OTHER buffer (race-free: read buffer is never written intra-tile);
// one vmcnt(0) at tile end, issued ~4 phases after the loads (stall-free).
__global__ __launch_bounds__(512, 2)
void w8a8_gemm_kernel(const int8_t* __restrict__ x,
                      const int8_t* __restrict__ w,
                      const float* __restrict__ scale,
                      const float* __restrict__ bias,
                      float* __restrict__ out)
{
    __shared__ int8_t lA[2 * 256 * 128];   // [buf][row][128B]  64 KB
    __shared__ int8_t lB[2 * 256 * 128];   // 64 KB  (total 128 KB)

    const int tid = threadIdx.x;
    const int wv  = tid >> 6;
    const int l   = tid & 63;
    const int wrow = (wv >> 2) * 128;      // wave A-row base (0 / 128)
    const int wcol = (wv & 3) * 64;        // wave B-row (out-col) base

    const int bn = blockIdx.x;             // 0..15
    const int bm = blockIdx.y;             // 0..31

    const int8_t* baseA = x + (size_t)bm * BM * IN_F;
    const int8_t* baseB = w + (size_t)bn * BN * IN_F;

    // ---- staging addressing (T2 swizzle: LDS[row][cb] = global(row, cb^((row&7)<<4)))
    // gload_lds dest is linear (base + lane*16); pre-swizzle the GLOBAL column.
    const int seg0 = wv * 2, seg1 = wv * 2 + 1;   // 16 segments of 8 rows per half-tile
    const int r8   = l >> 3;                       // row-within-segment 0..7
    const int swc  = (((l & 7) ^ r8) << 4);        // swizzled source col-byte

    // ---- fragment read addressing
    const int fr  = l & 15;
    const int xk  = (l & 7) << 4;                  // read-side swizzle key (row&7 == l&7)
    const int cb0 = (l >> 4) << 4;                 // 0,16,32,48

    int32x4 acc[8][4];
#pragma unroll
    for (int m = 0; m < 8; ++m)
#pragma unroll
        for (int n = 0; n < 4; ++n)
            acc[m][n] = (int32x4){0, 0, 0, 0};

    int32x4 aF[4][2];   // 4 m-frags x 2 k-steps
    int32x4 bF[2][2];   // 2 n-frags x 2 k-steps

    // stage one half-tile (2 x global_load_lds per thread)
    auto stage_half = [&](int h4) {
        const int kt_ = h4 >> 2;
        const int wh_ = h4 & 3;                    // 0:A0 1:A1 2:B0 3:B1
        const int8_t* sb = (wh_ < 2) ? baseA : baseB;
        int8_t* db = ((wh_ < 2) ? lA : lB) + ((kt_ & 1) << 15) + ((wh_ & 1) << 14);
        const size_t co = (size_t)kt_ * BK + swc;
        const size_t rb = (size_t)((wh_ & 1) * 128 + r8);
        __builtin_amdgcn_global_load_lds(
            (const __attribute__((address_space(1))) void*)(sb + (rb + seg0 * 8) * IN_F + co),
            (__attribute__((address_space(3))) void*)(db + seg0 * 1024), 16, 0, 0);
        __builtin_amdgcn_global_load_lds(
            (const __attribute__((address_space(1))) void*)(sb + (rb + seg1 * 8) * IN_F + co),
            (__attribute__((address_space(3))) void*)(db + seg1 * 1024), 16, 0, 0);
    };
    auto stage_tile = [&](int tt) {   // all 4 halves -> buffer tt&1
        stage_half(4 * tt + 0); stage_half(4 * tt + 1);
        stage_half(4 * tt + 2); stage_half(4 * tt + 3);
    };

#define LOADA(MH)                                                                     \
    do {                                                                              \
        _Pragma("unroll") for (int j = 0; j < 4; ++j)                                 \
        _Pragma("unroll") for (int ks = 0; ks < 2; ++ks)                              \
            aF[j][ks] = *(const int32x4*)&lAb[(wrow + ((MH)*4 + j) * 16 + fr) * 128 + \
                                              (((ks * 64) + cb0) ^ xk)];              \
    } while (0)

#define LOADB(NH)                                                                     \
    do {                                                                              \
        _Pragma("unroll") for (int j2 = 0; j2 < 2; ++j2)                              \
        _Pragma("unroll") for (int ks = 0; ks < 2; ++ks)                              \
            bF[j2][ks] = *(const int32x4*)&lBb[(wcol + ((NH)*2 + j2) * 16 + fr) * 128 + \
                                               (((ks * 64) + cb0) ^ xk)];             \
    } while (0)

#define MMAQ(MH, NH)                                                                  \
    do {                                                                              \
        _Pragma("unroll") for (int j = 0; j < 4; ++j)                                 \
        _Pragma("unroll") for (int j2 = 0; j2 < 2; ++j2)                              \
        _Pragma("unroll") for (int ks = 0; ks < 2; ++ks)                              \
            acc[(MH)*4 + j][(NH)*2 + j2] = __builtin_amdgcn_mfma_i32_16x16x64_i8(     \
                aF[j][ks], bF[j2][ks], acc[(MH)*4 + j][(NH)*2 + j2], 0, 0, 0);        \
    } while (0)

#define PH(MH, NH)                                                                    \
    do {                                                                              \
        __builtin_amdgcn_s_barrier();                                                 \
        __builtin_amdgcn_s_setprio(1);                                                \
        MMAQ(MH, NH);                                                                 \
        __builtin_amdgcn_s_setprio(0);                                                \
        __builtin_amdgcn_s_barrier();                                                 \
    } while (0)

    // ---- prologue: tile 0 fully staged ----
    stage_tile(0);
    asm volatile("s_waitcnt vmcnt(0)" ::: "memory");
    __builtin_amdgcn_s_barrier();

    // ---- main loop: 4 gray-code phases per K-tile ----
    for (int t = 0; t < NT; ++t) {
        const int8_t* lAb = lA + ((t & 1) << 15);
        const int8_t* lBb = lB + ((t & 1) << 15);
        const bool pre = (t + 1 < NT);
        if (pre) stage_tile(t + 1);          // -> buffer (t+1)&1, never read this tile

        LOADA(0); LOADB(0); PH(0, 0);        // quadrant (0,0)
        LOADB(1);           PH(0, 1);        // (0,1)
        LOADA(1);           PH(1, 1);        // (1,1)
        LOADB(0);                            // (1,0) + tile-end drain
        __builtin_amdgcn_s_barrier();
        __builtin_amdgcn_s_setprio(1);
        MMAQ(1, 0);
        __builtin_amdgcn_s_setprio(0);
        if (pre) asm volatile("s_waitcnt vmcnt(0)" ::: "memory");  // loads issued 4 phases ago
        __builtin_amdgcn_s_barrier();
    }

    // ---- epilogue: dequant + fp16-rounding emulation, store f32 ----
    // C/D layout (verified): col = lane&15 (fr), row = (lane>>4)*4 + reg
    const int r0 = (l >> 4) << 2;
#pragma unroll
    for (int n = 0; n < 4; ++n) {
        const int col = bn * BN + wcol + n * 16 + fr;
        const float sc  = scale[col];
        const __half bs = __float2half(bias[col]);
#pragma unroll
        for (int m = 0; m < 8; ++m) {
            const int rowb = bm * BM + wrow + m * 16 + r0;
#pragma unroll
            for (int r = 0; r < 4; ++r) {
                __half h = __float2half((float)acc[m][n][r] * sc);
                out[(size_t)(rowb + r) * OUT_F + col] = __half2float(__hadd(h, bs));
            }
        }
    }
#undef LOADA
#undef LOADB
#undef MMAQ
#undef PH
}

// second tuple output: copy of bias (f32 container)
__global__ void bias_copy_kernel(const float* __restrict__ bias, float* __restrict__ dst)
{
    const int i = blockIdx.x * 256 + threadIdx.x;
    if (i < OUT_F) dst[i] = bias[i];
}

extern "C" void kernel_launch(void* const* d_in, const int* in_sizes, int n_in,
                              void* d_out, int out_size, void* d_ws, size_t ws_size,
                              hipStream_t stream)
{
    const int*   x32   = (const int*)d_in[0];
    const int*   w32   = (const int*)d_in[1];
    const float* scale = (const float*)d_in[2];
    const float* bias  = (const float*)d_in[3];
    float* out = (float*)d_out;

    int8_t* x8 = (int8_t*)d_ws;
    int8_t* w8 = x8 + (size_t)TOKENS * IN_F;

    pack_kernel<<<2048, 256, 0, stream>>>(x32, (uint32_t*)x8, TOKENS * IN_F / 4);
    pack_kernel<<<2048, 256, 0, stream>>>(w32, (uint32_t*)w8, OUT_F * IN_F / 4);

    dim3 grid(OUT_F / BN, TOKENS / BM);   // (16, 32) = 512 blocks
    w8a8_gemm_kernel<<<grid, 512, 0, stream>>>(x8, w8, scale, bias, out);
    bias_copy_kernel<<<OUT_F / 256, 256, 0, stream>>>(bias, out + (size_t)TOKENS * OUT_F);
}

// Round 7
// 211.559 us; speedup vs baseline: 1.3130x; 1.0966x over previous
//
#include <hip/hip_runtime.h>
#include <hip/hip_fp16.h>
#include <stdint.h>

typedef __attribute__((ext_vector_type(4))) int int32x4;

#define TOKENS 8192
#define IN_F   4096
#define OUT_F  4096
#define BM 256
#define BN 256
#define BK 128              // int8 per K-tile = 128 B rows
#define NT (IN_F / BK)      // 32 K-tiles

// ---------------- pack int32 container -> int8 (coalesced) ----------------
__global__ __launch_bounds__(256)
void pack_kernel(const int* __restrict__ src, uint32_t* __restrict__ dst, int n4)
{
    for (int i = blockIdx.x * 256 + threadIdx.x; i < n4; i += gridDim.x * 256) {
        int32x4 v = ((const int32x4*)src)[i];           // 16 B/lane coalesced
        dst[i] = (uint32_t)(v[0] & 0xff) | ((uint32_t)(v[1] & 0xff) << 8) |
                 ((uint32_t)(v[2] & 0xff) << 16) | ((uint32_t)v[3] << 24);
    }
}

// ------------- 256x256 i8 GEMM, counted-vmcnt 4-phase schedule -------------
// 512 threads = 8 waves. Per phase: quadrant (MH,NH) of C (128x128), waves
// tiled 4M x 2N inside the quadrant -> each phase reads ONLY A-half MH and
// B-half NH. Stage schedule (tile t): w1:A1(t+1) w2:B0(t+1) w3:A0(t+2)
// w4:B1(t+2); vmcnt(4) in w4-pre (the 4 outstanding = t+2 loads), full drain
// only at tail. Race-proof: live-buffer halves overwritten (w3/w4) had their
// last ds_read >=1 closing barrier earlier; cross-wave visibility via the
// (vmcnt, barrier) pair preceding the consuming tile's pre-region.
__global__ __launch_bounds__(512, 2)
void w8a8_gemm_kernel(const int8_t* __restrict__ x,
                      const int8_t* __restrict__ w,
                      const float* __restrict__ scale,
                      const float* __restrict__ bias,
                      float* __restrict__ out)
{
    __shared__ int8_t lA[2 * 2 * 128 * 128];   // [buf][half][row][128B] 64 KB
    __shared__ int8_t lB[2 * 2 * 128 * 128];   // 64 KB (total 128 KB)

    const int tid = threadIdx.x;
    const int wv  = tid >> 6;
    const int l   = tid & 63;
    const int wqm = wv >> 1;               // 0..3  (32-row strip in quadrant)
    const int wqn = wv & 1;                // 0..1  (64-col strip in quadrant)

    const int bn = blockIdx.x;             // 0..15
    const int bm = blockIdx.y;             // 0..31

    const int8_t* baseA = x + (size_t)bm * BM * IN_F;
    const int8_t* baseB = w + (size_t)bn * BN * IN_F;

    // staging: T2 swizzle via pre-swizzled global source (rule 21)
    const int seg0 = wv * 2, seg1 = wv * 2 + 1;   // 16 segs x 8 rows per half
    const int r8   = l >> 3;
    const int swc  = (((l & 7) ^ r8) << 4);

    // fragment read addressing
    const int fr  = l & 15;
    const int xk  = (l & 7) << 4;
    const int cb0 = (l >> 4) << 4;

    int32x4 acc[2][2][2][4];
#pragma unroll
    for (int a0 = 0; a0 < 2; ++a0)
#pragma unroll
        for (int a1 = 0; a1 < 2; ++a1)
#pragma unroll
            for (int a2 = 0; a2 < 2; ++a2)
#pragma unroll
                for (int a3 = 0; a3 < 4; ++a3)
                    acc[a0][a1][a2][a3] = (int32x4){0, 0, 0, 0};

    int32x4 aF[2][2];      // 2 mi x 2 ks
    int32x4 bF0[4][2];     // NH=0 frags, held whole tile (reused at w4)
    int32x4 bF1[4][2];     // NH=1 frags

    // stage one half-tile: h4 = tile*4 + {0:A0 1:A1 2:B0 3:B1}
    auto stage_half = [&](int h4) {
        const int kt_ = h4 >> 2;
        const int wh_ = h4 & 3;
        const int8_t* sb = (wh_ < 2) ? baseA : baseB;
        int8_t* db = ((wh_ < 2) ? lA : lB) + ((kt_ & 1) << 15) + ((wh_ & 1) << 14);
        const size_t co = (size_t)kt_ * BK + swc;
        const size_t rb = (size_t)((wh_ & 1) * 128 + r8);
        __builtin_amdgcn_global_load_lds(
            (const __attribute__((address_space(1))) void*)(sb + (rb + seg0 * 8) * IN_F + co),
            (__attribute__((address_space(3))) void*)(db + seg0 * 1024), 16, 0, 0);
        __builtin_amdgcn_global_load_lds(
            (const __attribute__((address_space(1))) void*)(sb + (rb + seg1 * 8) * IN_F + co),
            (__attribute__((address_space(3))) void*)(db + seg1 * 1024), 16, 0, 0);
    };

#define LDA(MH)                                                                        \
    do {                                                                               \
        _Pragma("unroll") for (int mi = 0; mi < 2; ++mi)                               \
        _Pragma("unroll") for (int ks = 0; ks < 2; ++ks)                               \
            aF[mi][ks] = *(const int32x4*)&lAb[((MH) << 14) +                          \
                (wqm * 32 + mi * 16 + fr) * 128 + (((ks * 64) + cb0) ^ xk)];           \
    } while (0)

#define LDB(NH, DST)                                                                   \
    do {                                                                               \
        _Pragma("unroll") for (int ni = 0; ni < 4; ++ni)                               \
        _Pragma("unroll") for (int ks = 0; ks < 2; ++ks)                               \
            DST[ni][ks] = *(const int32x4*)&lBb[((NH) << 14) +                         \
                (wqn * 64 + ni * 16 + fr) * 128 + (((ks * 64) + cb0) ^ xk)];           \
    } while (0)

#define MMAQ(MH, NH, BF)                                                               \
    do {                                                                               \
        _Pragma("unroll") for (int mi = 0; mi < 2; ++mi)                               \
        _Pragma("unroll") for (int ni = 0; ni < 4; ++ni)                               \
        _Pragma("unroll") for (int ks = 0; ks < 2; ++ks)                               \
            acc[MH][NH][mi][ni] = __builtin_amdgcn_mfma_i32_16x16x64_i8(               \
                aF[mi][ks], BF[ni][ks], acc[MH][NH][mi][ni], 0, 0, 0);                 \
    } while (0)

#define PH(MH, NH, BF)                                                                 \
    do {                                                                               \
        __builtin_amdgcn_s_barrier();                                                  \
        asm volatile("s_waitcnt lgkmcnt(0)" ::: "memory");                             \
        __builtin_amdgcn_s_setprio(1);                                                 \
        MMAQ(MH, NH, BF);                                                              \
        __builtin_amdgcn_s_setprio(0);                                                 \
        __builtin_amdgcn_s_barrier();                                                  \
    } while (0)

    // ---- prologue: A0(0),B1(0),A1(0),B0(0),A0(1),B1(1); cover pair for t=0 ----
    stage_half(0); stage_half(3); stage_half(1); stage_half(2);
    stage_half(4); stage_half(7);
    asm volatile("s_waitcnt vmcnt(4)" ::: "memory");   // newest 4 = A0(1),B1(1)
    __builtin_amdgcn_s_barrier();

    // ---- main loop ----
    for (int t = 0; t < NT; ++t) {
        const int8_t* lAb = lA + ((t & 1) << 15);
        const int8_t* lBb = lB + ((t & 1) << 15);

        // w1: quadrant (0,0) — reads A0(t), B0(t)
        LDA(0); LDB(0, bF0);
        if (t + 1 < NT) stage_half(4 * (t + 1) + 1);   // A1(t+1) -> other parity
        PH(0, 0, bF0);

        // w2: (0,1) — reads B1(t)
        LDB(1, bF1);
        if (t + 1 < NT) stage_half(4 * (t + 1) + 2);   // B0(t+1) -> other parity
        PH(0, 1, bF1);

        // w3: (1,1) — reads A1(t); overwrites A0 (last read ended w1-close... w2-close)
        LDA(1);
        if (t + 2 < NT) stage_half(4 * (t + 2) + 0);   // A0(t+2) -> live parity, safe
        PH(1, 1, bF1);

        // w4: (1,0) — register-only (bF0 held); overwrites B1 (last read w3)
        if (t + 2 < NT) stage_half(4 * (t + 2) + 3);   // B1(t+2) -> live parity, safe
        if (t + 2 < NT)      asm volatile("s_waitcnt vmcnt(4)" ::: "memory");
        else if (t + 1 < NT) asm volatile("s_waitcnt vmcnt(0)" ::: "memory");
        PH(1, 0, bF0);
    }

    // ---- epilogue: dequant + fp16-rounding emulation, store f32 ----
    // C/D: col = lane&15 (fr), row = (lane>>4)*4 + reg
    const int r0 = (l >> 4) << 2;
#pragma unroll
    for (int NH = 0; NH < 2; ++NH)
#pragma unroll
        for (int ni = 0; ni < 4; ++ni) {
            const int col = bn * BN + NH * 128 + wqn * 64 + ni * 16 + fr;
            const float sc  = scale[col];
            const __half bs = __float2half(bias[col]);
#pragma unroll
            for (int MH = 0; MH < 2; ++MH)
#pragma unroll
                for (int mi = 0; mi < 2; ++mi) {
                    const int rowb = bm * BM + MH * 128 + wqm * 32 + mi * 16 + r0;
#pragma unroll
                    for (int r = 0; r < 4; ++r) {
                        __half h = __float2half((float)acc[MH][NH][mi][ni][r] * sc);
                        out[(size_t)(rowb + r) * OUT_F + col] = __half2float(__hadd(h, bs));
                    }
                }
        }
#undef LDA
#undef LDB
#undef MMAQ
#undef PH
}

// second tuple output: copy of bias (f32 container)
__global__ void bias_copy_kernel(const float* __restrict__ bias, float* __restrict__ dst)
{
    const int i = blockIdx.x * 256 + threadIdx.x;
    if (i < OUT_F) dst[i] = bias[i];
}

extern "C" void kernel_launch(void* const* d_in, const int* in_sizes, int n_in,
                              void* d_out, int out_size, void* d_ws, size_t ws_size,
                              hipStream_t stream)
{
    const int*   x32   = (const int*)d_in[0];
    const int*   w32   = (const int*)d_in[1];
    const float* scale = (const float*)d_in[2];
    const float* bias  = (const float*)d_in[3];
    float* out = (float*)d_out;

    int8_t* x8 = (int8_t*)d_ws;
    int8_t* w8 = x8 + (size_t)TOKENS * IN_F;

    pack_kernel<<<2048, 256, 0, stream>>>(x32, (uint32_t*)x8, TOKENS * IN_F / 4);
    pack_kernel<<<2048, 256, 0, stream>>>(w32, (uint32_t*)w8, OUT_F * IN_F / 4);

    dim3 grid(OUT_F / BN, TOKENS / BM);   // (16, 32) = 512 blocks
    w8a8_gemm_kernel<<<grid, 512, 0, stream>>>(x8, w8, scale, bias, out);
    bias_copy_kernel<<<OUT_F / 256, 256, 0, stream>>>(bias, out + (size_t)TOKENS * OUT_F);
}

// Round 8
// 196.285 us; speedup vs baseline: 1.4152x; 1.0778x over previous
//
#include <hip/hip_runtime.h>
#include <hip/hip_fp16.h>
#include <stdint.h>

typedef __attribute__((ext_vector_type(4))) int int32x4;
typedef __attribute__((ext_vector_type(4))) float float32x4;

#define TOKENS 8192
#define IN_F   4096
#define OUT_F  4096
#define BM 256
#define BN 256
#define BK 128              // int8 per K-tile = 128 B rows
#define NT (IN_F / BK)      // 32 K-tiles
#define ESTR 260            // epilogue LDS row stride (f32): 260%32=4 -> 2-way = free

// ------- fused pack: int32->int8 for x and w, plus bias tuple-output -------
__global__ __launch_bounds__(256)
void pack_all_kernel(const int* __restrict__ x32, const int* __restrict__ w32,
                     const float* __restrict__ bias,
                     uint32_t* __restrict__ x8, uint32_t* __restrict__ w8,
                     float* __restrict__ bias_out)
{
    const int gid = blockIdx.x * 256 + threadIdx.x;
    if (gid < OUT_F / 4)
        ((float32x4*)bias_out)[gid] = ((const float32x4*)bias)[gid];

    const int nx4 = TOKENS * IN_F / 4;
    const int nw4 = OUT_F * IN_F / 4;
    for (int i = gid; i < nx4 + nw4; i += gridDim.x * 256) {
        const int* s; uint32_t* d; int j;
        if (i < nx4) { s = x32; d = x8; j = i; }
        else         { s = w32; d = w8; j = i - nx4; }
        int32x4 v = ((const int32x4*)s)[j];               // 16 B/lane coalesced
        d[j] = (uint32_t)(v[0] & 0xff) | ((uint32_t)(v[1] & 0xff) << 8) |
               ((uint32_t)(v[2] & 0xff) << 16) | ((uint32_t)v[3] << 24);
    }
}

// ------------- 256x256 i8 GEMM, counted-vmcnt 4-phase schedule -------------
// (verified round 7) + LDS-staged coalesced epilogue (this round).
__global__ __launch_bounds__(512, 2)
void w8a8_gemm_kernel(const int8_t* __restrict__ x,
                      const int8_t* __restrict__ w,
                      const float* __restrict__ scale,
                      const float* __restrict__ bias,
                      float* __restrict__ out)
{
    __shared__ int8_t smem[131072];            // staging: lA | lB ; epilogue: [64][260] i32
    int8_t* lA = smem;                         // [buf][half][128][128B] 64 KB
    int8_t* lB = smem + 65536;                 // 64 KB

    const int tid = threadIdx.x;
    const int wv  = tid >> 6;
    const int l   = tid & 63;
    const int wqm = wv >> 1;               // 0..3  (32-row strip in quadrant)
    const int wqn = wv & 1;                // 0..1  (64-col strip in quadrant)

    const int bn = blockIdx.x;             // 0..15
    const int bm = blockIdx.y;             // 0..31

    const int8_t* baseA = x + (size_t)bm * BM * IN_F;
    const int8_t* baseB = w + (size_t)bn * BN * IN_F;

    // staging: T2 swizzle via pre-swizzled global source (rule 21)
    const int seg0 = wv * 2, seg1 = wv * 2 + 1;   // 16 segs x 8 rows per half
    const int r8   = l >> 3;
    const int swc  = (((l & 7) ^ r8) << 4);

    // fragment read addressing
    const int fr  = l & 15;
    const int xk  = (l & 7) << 4;
    const int cb0 = (l >> 4) << 4;

    int32x4 acc[2][2][2][4];
#pragma unroll
    for (int a0 = 0; a0 < 2; ++a0)
#pragma unroll
        for (int a1 = 0; a1 < 2; ++a1)
#pragma unroll
            for (int a2 = 0; a2 < 2; ++a2)
#pragma unroll
                for (int a3 = 0; a3 < 4; ++a3)
                    acc[a0][a1][a2][a3] = (int32x4){0, 0, 0, 0};

    int32x4 aF[2][2];      // 2 mi x 2 ks
    int32x4 bF0[4][2];     // NH=0 frags, held whole tile (reused at w4)
    int32x4 bF1[4][2];     // NH=1 frags

    auto stage_half = [&](int h4) {
        const int kt_ = h4 >> 2;
        const int wh_ = h4 & 3;                    // 0:A0 1:A1 2:B0 3:B1
        const int8_t* sb = (wh_ < 2) ? baseA : baseB;
        int8_t* db = ((wh_ < 2) ? lA : lB) + ((kt_ & 1) << 15) + ((wh_ & 1) << 14);
        const size_t co = (size_t)kt_ * BK + swc;
        const size_t rb = (size_t)((wh_ & 1) * 128 + r8);
        __builtin_amdgcn_global_load_lds(
            (const __attribute__((address_space(1))) void*)(sb + (rb + seg0 * 8) * IN_F + co),
            (__attribute__((address_space(3))) void*)(db + seg0 * 1024), 16, 0, 0);
        __builtin_amdgcn_global_load_lds(
            (const __attribute__((address_space(1))) void*)(sb + (rb + seg1 * 8) * IN_F + co),
            (__attribute__((address_space(3))) void*)(db + seg1 * 1024), 16, 0, 0);
    };

#define LDA(MH)                                                                        \
    do {                                                                               \
        _Pragma("unroll") for (int mi = 0; mi < 2; ++mi)                               \
        _Pragma("unroll") for (int ks = 0; ks < 2; ++ks)                               \
            aF[mi][ks] = *(const int32x4*)&lAb[((MH) << 14) +                          \
                (wqm * 32 + mi * 16 + fr) * 128 + (((ks * 64) + cb0) ^ xk)];           \
    } while (0)

#define LDB(NH, DST)                                                                   \
    do {                                                                               \
        _Pragma("unroll") for (int ni = 0; ni < 4; ++ni)                               \
        _Pragma("unroll") for (int ks = 0; ks < 2; ++ks)                               \
            DST[ni][ks] = *(const int32x4*)&lBb[((NH) << 14) +                         \
                (wqn * 64 + ni * 16 + fr) * 128 + (((ks * 64) + cb0) ^ xk)];           \
    } while (0)

#define MMAQ(MH, NH, BF)                                                               \
    do {                                                                               \
        _Pragma("unroll") for (int mi = 0; mi < 2; ++mi)                               \
        _Pragma("unroll") for (int ni = 0; ni < 4; ++ni)                               \
        _Pragma("unroll") for (int ks = 0; ks < 2; ++ks)                               \
            acc[MH][NH][mi][ni] = __builtin_amdgcn_mfma_i32_16x16x64_i8(               \
                aF[mi][ks], BF[ni][ks], acc[MH][NH][mi][ni], 0, 0, 0);                 \
    } while (0)

#define PH(MH, NH, BF)                                                                 \
    do {                                                                               \
        __builtin_amdgcn_s_barrier();                                                  \
        asm volatile("s_waitcnt lgkmcnt(0)" ::: "memory");                             \
        __builtin_amdgcn_s_setprio(1);                                                 \
        MMAQ(MH, NH, BF);                                                              \
        __builtin_amdgcn_s_setprio(0);                                                 \
        __builtin_amdgcn_s_barrier();                                                  \
    } while (0)

    // ---- prologue: tile0 fully + A0(1),B1(1) ----
    stage_half(0); stage_half(3); stage_half(1); stage_half(2);
    stage_half(4); stage_half(7);
    asm volatile("s_waitcnt vmcnt(4)" ::: "memory");   // tile0 landed
    __builtin_amdgcn_s_barrier();

    // ---- main loop (round-7-verified) ----
    for (int t = 0; t < NT; ++t) {
        const int8_t* lAb = lA + ((t & 1) << 15);
        const int8_t* lBb = lB + ((t & 1) << 15);

        LDA(0); LDB(0, bF0);
        if (t + 1 < NT) stage_half(4 * (t + 1) + 1);   // A1(t+1)
        PH(0, 0, bF0);

        LDB(1, bF1);
        if (t + 1 < NT) stage_half(4 * (t + 1) + 2);   // B0(t+1)
        PH(0, 1, bF1);

        LDA(1);
        if (t + 2 < NT) stage_half(4 * (t + 2) + 0);   // A0(t+2)
        PH(1, 1, bF1);

        if (t + 2 < NT) stage_half(4 * (t + 2) + 3);   // B1(t+2)
        if (t + 2 < NT)      asm volatile("s_waitcnt vmcnt(4)" ::: "memory");
        else if (t + 1 < NT) asm volatile("s_waitcnt vmcnt(0)" ::: "memory");
        PH(1, 0, bF0);
    }

    // ---- epilogue: LDS-staged, fully coalesced float4 stores ----
    // 4 chunks of 64 output rows; acc -> LDS [64][ESTR] i32 (2-way = free),
    // then 512 threads stream float4 (full 128B lines), dequant on the fly.
    __syncthreads();
    int* eL = (int*)smem;
    const int c4   = tid & 63;          // float4 col index within 256-col block
    const int rowt = tid >> 6;          // 0..7
    const float32x4 sc4 = ((const float32x4*)scale)[bn * 64 + c4];
    const float32x4 bf4 = ((const float32x4*)bias )[bn * 64 + c4];
    const __half bh[4] = { __float2half(bf4[0]), __float2half(bf4[1]),
                           __float2half(bf4[2]), __float2half(bf4[3]) };
    const int r0 = (l >> 4) << 2;
    const int wr0 = (wqm & 1) * 32 + r0;

    for (int c = 0; c < 4; ++c) {
        if ((wqm >> 1) == (c & 1)) {
            const int MH = c >> 1;
#pragma unroll
            for (int NH = 0; NH < 2; ++NH)
#pragma unroll
                for (int mi = 0; mi < 2; ++mi)
#pragma unroll
                    for (int ni = 0; ni < 4; ++ni)
#pragma unroll
                        for (int r = 0; r < 4; ++r)
                            eL[(wr0 + mi * 16 + r) * ESTR +
                               NH * 128 + wqn * 64 + ni * 16 + fr] = acc[MH][NH][mi][ni][r];
        }
        __syncthreads();
#pragma unroll
        for (int p = 0; p < 8; ++p) {
            const int rl = p * 8 + rowt;
            int32x4 v = *(const int32x4*)&eL[rl * ESTR + c4 * 4];
            float32x4 o;
#pragma unroll
            for (int j = 0; j < 4; ++j) {
                __half h = __float2half((float)v[j] * sc4[j]);
                o[j] = __half2float(__hadd(h, bh[j]));
            }
            const size_t rowg = (size_t)(bm * 256 + c * 64 + rl);
            ((float32x4*)out)[rowg * (OUT_F / 4) + bn * 64 + c4] = o;
        }
        __syncthreads();   // copy-out done before next chunk overwrites
    }
#undef LDA
#undef LDB
#undef MMAQ
#undef PH
}

extern "C" void kernel_launch(void* const* d_in, const int* in_sizes, int n_in,
                              void* d_out, int out_size, void* d_ws, size_t ws_size,
                              hipStream_t stream)
{
    const int*   x32   = (const int*)d_in[0];
    const int*   w32   = (const int*)d_in[1];
    const float* scale = (const float*)d_in[2];
    const float* bias  = (const float*)d_in[3];
    float* out = (float*)d_out;

    int8_t* x8 = (int8_t*)d_ws;
    int8_t* w8 = x8 + (size_t)TOKENS * IN_F;

    pack_all_kernel<<<3072, 256, 0, stream>>>(x32, w32, bias, (uint32_t*)x8, (uint32_t*)w8,
                                              out + (size_t)TOKENS * OUT_F);

    dim3 grid(OUT_F / BN, TOKENS / BM);   // (16, 32) = 512 blocks
    w8a8_gemm_kernel<<<grid, 512, 0, stream>>>(x8, w8, scale, bias, out);
}